// Round 10
// baseline (429.440 us; speedup 1.0000x reference)
//
#include <hip/hip_runtime.h>
#include <hip/hip_bf16.h>
#include <math.h>

#define N_ROWS 65536
#define ZDIM   256
#define KCODES 1024
#define IDX_OFF  (N_ROWS * ZDIM)        // 16777216
#define LOSS_OFF (IDX_OFF + N_ROWS)     // 16842752
#define ZQ_BLOCKS 2048
#define SLOTS 8

typedef unsigned int u32;
typedef unsigned short u16;
typedef __attribute__((ext_vector_type(8))) short bfrag;   // 8 bf16 (4 VGPR)
typedef __attribute__((ext_vector_type(4))) float ffrag;   // 4 fp32 acc

__device__ __forceinline__ u16 f2bf(float x) {
    __hip_bfloat16 h = __float2bfloat16(x);      // RN
    union { __hip_bfloat16 h; u16 u; } c; c.h = h; return c.u;
}

// async global->LDS DMA, 16B per lane, dest = wave-uniform base + lane*16
__device__ __forceinline__ void async16(const void* g, void* l) {
    __builtin_amdgcn_global_load_lds(
        (const __attribute__((address_space(1))) u32*)g,
        (__attribute__((address_space(3))) u32*)l,
        16, 0, 0);
}

// ---------------- numpy-pairwise helpers (256 cols) ----------------
__device__ __forceinline__ float np_pw128_sq(const float* __restrict__ p) {
    float r[8];
#pragma unroll
    for (int j = 0; j < 8; ++j) r[j] = __fmul_rn(p[j], p[j]);
    for (int i = 8; i < 128; i += 8) {
#pragma unroll
        for (int j = 0; j < 8; ++j)
            r[j] = __fadd_rn(r[j], __fmul_rn(p[i + j], p[i + j]));
    }
    float a = __fadd_rn(__fadd_rn(r[0], r[1]), __fadd_rn(r[2], r[3]));
    float b = __fadd_rn(__fadd_rn(r[4], r[5]), __fadd_rn(r[6], r[7]));
    return __fadd_rn(a, b);
}

__device__ __forceinline__ float pw128_abs(const float* __restrict__ p) {
    float r[8];
#pragma unroll
    for (int j = 0; j < 8; ++j) r[j] = fabsf(p[j]);
    for (int i = 8; i < 128; i += 8) {
#pragma unroll
        for (int j = 0; j < 8; ++j) r[j] += fabsf(p[i + j]);
    }
    return ((r[0] + r[1]) + (r[2] + r[3])) + ((r[4] + r[5]) + (r[6] + r[7]));
}

// se for e rows (np-exact)
__global__ void rowsq_kernel(const float* __restrict__ x, float* __restrict__ s, int nrows) {
    int r = blockIdx.x * blockDim.x + threadIdx.x;
    if (r >= nrows) return;
    const float* p = x + (size_t)r * ZDIM;
    s[r] = __fadd_rn(np_pw128_sq(p), np_pw128_sq(p + 128));
}

// sz (np-exact) + per-row rigorous eps for the 1-pass bf16 bound:
// |d~ - d_np| <= 2*S1*3.83e-6 + 4e-5  ->  eps = S1*8.4e-6 + 1.2e-4 (margin)
__global__ void rowsq_eps_kernel(const float* __restrict__ x, float* __restrict__ s,
                                 float* __restrict__ epsr) {
    int r = blockIdx.x * blockDim.x + threadIdx.x;
    const float* p = x + (size_t)r * ZDIM;
    s[r] = __fadd_rn(np_pw128_sq(p), np_pw128_sq(p + 128));
    float S1 = pw128_abs(p) + pw128_abs(p + 128);
    epsr[r] = fmaf(S1, 8.4e-6f, 1.2e-4f);
}

// ---------------- z -> bf16 (RN), row-major, into d_out z_q region ----------
__global__ __launch_bounds__(256) void split_z_kernel(
    const float* __restrict__ z, u16* __restrict__ zh) {
    int t = blockIdx.x * 256 + threadIdx.x;      // 2M threads x 8 elems
    int i = t * 8;
    float4 a = *(const float4*)(z + i);
    float4 b = *(const float4*)(z + i + 4);
    uint4 w;
    w.x = ((u32)f2bf(a.y) << 16) | f2bf(a.x);
    w.y = ((u32)f2bf(a.w) << 16) | f2bf(a.z);
    w.z = ((u32)f2bf(b.y) << 16) | f2bf(b.x);
    w.w = ((u32)f2bf(b.w) << 16) | f2bf(b.z);
    *(uint4*)(zh + i) = w;
}

// ---------------- e -> bf16, padded DMA-image layout ----------------
// ehp[slot][40 shorts], slot = (kc*4 + cq)*256 + (c&255); shorts 0..31 hold
// k = kc*32..+31 of code c = cq*256+(c&255); 32..39 pad (never read).
__global__ __launch_bounds__(256) void split_e_kernel(
    const float* __restrict__ e, u16* __restrict__ ehp) {
    int t = blockIdx.x * 256 + threadIdx.x;      // 65536 threads
    int c = t >> 6, kq = t & 63;
    float4 v = *(const float4*)(e + (size_t)c * ZDIM + kq * 4);
    ushort4 h;
    h.x = f2bf(v.x); h.y = f2bf(v.y); h.z = f2bf(v.z); h.w = f2bf(v.w);
    int kc = kq >> 3, cq = c >> 8, cl = c & 255;
    int slot = (kc * 4 + cq) * 256 + cl;
    *(ushort4*)(ehp + (size_t)slot * 40 + ((kq * 4) & 31)) = h;
}

// ---------------- 1-pass MFMA distance + candidate emission ----------------
// Grid 512 x 256 thr (4 waves). Wave w: rows wr0 = blk*128 + w*32 (rt=2 x 16),
// all codes via 4 cq x 8 kc. A-frags (zh) loaded ONCE into 64 VGPR. e staged
// by identity-DMA from ehp into stride-40 LDS (b128 reads at bank floor).
// Single barrier/phase; DMA(kc+1) flies under compute(kc).
// Frag maps (verified r9): A row=lane&15, k=(lane>>4)*8+j; B col=lane&15;
// D col=lane&15, row=(lane>>4)*4+reg.
__global__ __launch_bounds__(256) void mfma_argmin_kernel(
    const u16* __restrict__ zh, const u16* __restrict__ ehp,
    const float* __restrict__ sz, const float* __restrict__ se,
    const float* __restrict__ epsr, float* __restrict__ cqmin,
    int* __restrict__ cnt, int* __restrict__ cand) {
    __shared__ __align__(16) short ehL[2][10240];   // 40 KB
    __shared__ float sse[KCODES];                   //  4 KB
    const int tid = threadIdx.x;
    const int w = tid >> 6, lane = tid & 63;
    const int lr = lane & 15, lk = lane >> 4;
    const int wr0 = blockIdx.x * 128 + w * 32;

    *(float4*)(sse + tid * 4) = *(const float4*)(se + tid * 4);

    float szv[2][4], epsv[2][4];
#pragma unroll
    for (int rt = 0; rt < 2; ++rt)
#pragma unroll
        for (int j = 0; j < 4; ++j) {
            szv[rt][j]  = sz[wr0 + rt * 16 + lk * 4 + j];
            epsv[rt][j] = epsr[wr0 + rt * 16 + lk * 4 + j];
        }

    // A-fragments: once per kernel. 2 rt x 8 kc x 16B = 64 VGPR.
    bfrag A[2][8];
#pragma unroll
    for (int rt = 0; rt < 2; ++rt)
#pragma unroll
        for (int kc = 0; kc < 8; ++kc)
            A[rt][kc] = *(const bfrag*)(zh + (size_t)(wr0 + rt * 16 + lr) * ZDIM + kc * 32 + lk * 8);

    ffrag acc[2][16];

    // identity-DMA of one (cq,kc) 20KB image chunk into buf
    auto dma = [&](int cq, int kc, int buf) {
        const u16* src = ehp + (size_t)((kc * 4 + cq) * 256) * 40;
#pragma unroll
        for (int i = 0; i < 5; ++i) {
            const int n = w * 5 + i;
            async16(src + n * 512 + lane * 8, &ehL[buf][n * 512]);
        }
    };

#pragma unroll 1
    for (int cq = 0; cq < 4; ++cq) {
#pragma unroll
        for (int rt = 0; rt < 2; ++rt)
#pragma unroll
            for (int ct = 0; ct < 16; ++ct)
                acc[rt][ct] = (ffrag)(0.0f);

        dma(cq, 0, 0);
#pragma unroll
        for (int kc = 0; kc < 8; ++kc) {
            __syncthreads();                 // DMA(kc) complete; prev reads done
            if (kc < 7) dma(cq, kc + 1, (kc + 1) & 1);
            const short* bufp = ehL[kc & 1];
#pragma unroll
            for (int ct = 0; ct < 16; ++ct) {
                bfrag bh = *(const bfrag*)(bufp + ct * 640 + lr * 40 + lk * 8);
                acc[0][ct] = __builtin_amdgcn_mfma_f32_16x16x32_bf16(A[0][kc], bh, acc[0][ct], 0, 0, 0);
                acc[1][ct] = __builtin_amdgcn_mfma_f32_16x16x32_bf16(A[1][kc], bh, acc[1][ct], 0, 0, 0);
            }
        }

        // ---- epilogue: d~ = fl(fl(sz+se) - 2*m~), per-row min + emission ----
        float rmin[2][4];
#pragma unroll
        for (int rt = 0; rt < 2; ++rt)
#pragma unroll
            for (int j = 0; j < 4; ++j) rmin[rt][j] = __builtin_inff();
#pragma unroll
        for (int rt = 0; rt < 2; ++rt)
#pragma unroll
            for (int ct = 0; ct < 16; ++ct) {
                float sec = sse[cq * 256 + ct * 16 + lr];
#pragma unroll
                for (int j = 0; j < 4; ++j) {
                    float dd = __fsub_rn(__fadd_rn(szv[rt][j], sec), 2.0f * acc[rt][ct][j]);
                    rmin[rt][j] = fminf(rmin[rt][j], dd);
                }
            }
#pragma unroll
        for (int m = 1; m < 16; m <<= 1)
#pragma unroll
            for (int rt = 0; rt < 2; ++rt)
#pragma unroll
                for (int j = 0; j < 4; ++j)
                    rmin[rt][j] = fminf(rmin[rt][j], __shfl_xor(rmin[rt][j], m, 64));
        if (lr == 0) {
#pragma unroll
            for (int rt = 0; rt < 2; ++rt)
#pragma unroll
                for (int j = 0; j < 4; ++j)
                    cqmin[(size_t)(wr0 + rt * 16 + lk * 4 + j) * 4 + cq] = rmin[rt][j];
        }
#pragma unroll
        for (int rt = 0; rt < 2; ++rt)
#pragma unroll
            for (int j = 0; j < 4; ++j) {
                const float thr = fmaf(2.0f, epsv[rt][j], rmin[rt][j]);
                const int grow = wr0 + rt * 16 + lk * 4 + j;
#pragma unroll
                for (int ct = 0; ct < 16; ++ct) {
                    float dd = __fsub_rn(__fadd_rn(szv[rt][j], sse[cq * 256 + ct * 16 + lr]),
                                         2.0f * acc[rt][ct][j]);
                    if (dd <= thr) {
                        int s = atomicAdd(&cnt[grow * 4 + cq], 1);
                        if (s < SLOTS) cand[((size_t)grow * 4 + cq) * SLOTS + s] = cq * 256 + ct * 16 + lr;
                    }
                }
            }
    }
}

// ---------------- exact rescore (np/OpenBLAS-exact dots, first-index ties) ----
__global__ __launch_bounds__(256) void rescore_kernel(
    const float* __restrict__ z, const float* __restrict__ e,
    const float* __restrict__ sz, const float* __restrict__ se,
    const float* __restrict__ epsr, const float* __restrict__ cqmin,
    const int* __restrict__ cnt, const int* __restrict__ cand,
    int* __restrict__ out_idx, float* __restrict__ out_idx_f) {
    const int row = blockIdx.x * 256 + threadIdx.x;
    float m0 = cqmin[(size_t)row * 4 + 0];
    float m1 = cqmin[(size_t)row * 4 + 1];
    float m2 = cqmin[(size_t)row * 4 + 2];
    float m3 = cqmin[(size_t)row * 4 + 3];
    const float gmin = fminf(fminf(m0, m1), fminf(m2, m3));
    const float thr = fmaf(2.0f, epsr[row], gmin);

    int ncand = 0, first_c = 0;
    bool need_scan = false;
#pragma unroll
    for (int cq = 0; cq < 4; ++cq) {
        if (cqmin[(size_t)row * 4 + cq] <= thr) {
            int n = cnt[(size_t)row * 4 + cq];
            if (n > SLOTS) { need_scan = true; }
            else {
                for (int s = 0; s < n; ++s) {
                    int c = cand[((size_t)row * 4 + cq) * SLOTS + s];
                    if (ncand == 0) first_c = c;
                    ++ncand;
                }
            }
        }
    }
    int bi;
    if (!need_scan && ncand == 1) {
        bi = first_c;
    } else {
        const float szr = sz[row];
        const float* zr = z + (size_t)row * ZDIM;
        float bd = __builtin_inff();
        bi = 0x7fffffff;
#pragma unroll 1
        for (int cq = 0; cq < 4; ++cq) {
            if (cqmin[(size_t)row * 4 + cq] > thr) continue;
            int n = cnt[(size_t)row * 4 + cq];
            if (n > SLOTS) {
                for (int c = cq * 256; c < cq * 256 + 256; ++c) {
                    const float* er = e + (size_t)c * ZDIM;
                    float m = 0.0f;
                    for (int k = 0; k < ZDIM; ++k) m = fmaf(zr[k], er[k], m);
                    float d = __fsub_rn(__fadd_rn(szr, se[c]), 2.0f * m);
                    if (d < bd || (d == bd && c < bi)) { bd = d; bi = c; }
                }
            } else {
                for (int s = 0; s < n; ++s) {
                    int c = cand[((size_t)row * 4 + cq) * SLOTS + s];
                    const float* er = e + (size_t)c * ZDIM;
                    float m = 0.0f;
                    for (int k = 0; k < ZDIM; ++k) m = fmaf(zr[k], er[k], m);
                    float d = __fsub_rn(__fadd_rn(szr, se[c]), 2.0f * m);
                    if (d < bd || (d == bd && c < bi)) { bd = d; bi = c; }
                }
            }
        }
    }
    out_idx[row] = bi;
    out_idx_f[row] = (float)bi;
}

// ---------------- z_q_st + loss partial (no atomics) ----------------
__global__ __launch_bounds__(256) void zq_loss_kernel(
    const float* __restrict__ z, const float* __restrict__ e,
    const int* __restrict__ idx, float* __restrict__ out,
    double* __restrict__ partial) {
    const int tid = threadIdx.x;
    const int rl  = tid >> 6;
    const int ln  = tid & 63;
    const int row0 = blockIdx.x * 32;

    float acc = 0.0f;
#pragma unroll
    for (int it = 0; it < 8; ++it) {
        int row = row0 + it * 4 + rl;
        int code = idx[row];
        const float4 vz = *(const float4*)(z + (size_t)row  * ZDIM + ln * 4);
        const float4 vq = *(const float4*)(e + (size_t)code * ZDIM + ln * 4);
        float4 o;
        float dx = __fsub_rn(vq.x, vz.x);
        float dy = __fsub_rn(vq.y, vz.y);
        float dz_ = __fsub_rn(vq.z, vz.z);
        float dw = __fsub_rn(vq.w, vz.w);
        o.x = __fadd_rn(vz.x, dx);
        o.y = __fadd_rn(vz.y, dy);
        o.z = __fadd_rn(vz.z, dz_);
        o.w = __fadd_rn(vz.w, dw);
        *(float4*)(out + (size_t)row * ZDIM + ln * 4) = o;
        acc = __fadd_rn(acc, __fmul_rn(dx, dx));
        acc = __fadd_rn(acc, __fmul_rn(dy, dy));
        acc = __fadd_rn(acc, __fmul_rn(dz_, dz_));
        acc = __fadd_rn(acc, __fmul_rn(dw, dw));
    }

    __shared__ double red[256];
    red[tid] = (double)acc;
    __syncthreads();
#pragma unroll
    for (int s = 128; s > 0; s >>= 1) {
        if (tid < s) red[tid] += red[tid + s];
        __syncthreads();
    }
    if (tid == 0) partial[blockIdx.x] = red[0];
}

__global__ __launch_bounds__(256) void loss_final_kernel(
    const double* __restrict__ partial, float* __restrict__ out_loss) {
    const int tid = threadIdx.x;
    double s = 0.0;
    for (int i = tid; i < ZQ_BLOCKS; i += 256) s += partial[i];
    __shared__ double red[256];
    red[tid] = s;
    __syncthreads();
#pragma unroll
    for (int st = 128; st > 0; st >>= 1) {
        if (tid < st) red[tid] += red[tid + st];
        __syncthreads();
    }
    if (tid == 0) {
        double M = red[0] / 16777216.0;
        float m32 = (float)M;
        out_loss[0] = __fadd_rn(m32, __fmul_rn(0.25f, m32));
    }
}

extern "C" void kernel_launch(void* const* d_in, const int* in_sizes, int n_in,
                              void* d_out, int out_size, void* d_ws, size_t ws_size,
                              hipStream_t stream) {
    const float* z = (const float*)d_in[0];
    const float* e = (const float*)d_in[1];
    float* out = (float*)d_out;
    char* ws = (char*)d_ws;

    size_t off = 0;
    double* partial = (double*)(ws + off); off += ZQ_BLOCKS * sizeof(double);      // 16 KB
    float*  sz      = (float*) (ws + off); off += (size_t)N_ROWS * 4;              // 256 KB
    float*  epsr    = (float*) (ws + off); off += (size_t)N_ROWS * 4;              // 256 KB
    float*  se      = (float*) (ws + off); off += (size_t)KCODES * 4;              // 4 KB
    int*    idx     = (int*)   (ws + off); off += (size_t)N_ROWS * 4;              // 256 KB
    u16*    ehp     = (u16*)   (ws + off); off += (size_t)32 * 256 * 40 * 2;       // 640 KB
    float*  cqmin   = (float*) (ws + off); off += (size_t)N_ROWS * 4 * 4;          // 1 MB
    int*    cnt     = (int*)   (ws + off); off += (size_t)N_ROWS * 4 * 4;          // 1 MB
    int*    cand    = (int*)   (ws + off); off += (size_t)N_ROWS * 4 * SLOTS * 4;  // 8 MB

    u16* zh = (u16*)out;   // bf16 z in d_out z_q region; zq_loss overwrites later

    hipMemsetAsync(cnt, 0, (size_t)N_ROWS * 4 * 4, stream);
    split_z_kernel<<<8192, 256, 0, stream>>>(z, zh);
    split_e_kernel<<<256, 256, 0, stream>>>(e, ehp);
    rowsq_eps_kernel<<<N_ROWS / 256, 256, 0, stream>>>(z, sz, epsr);
    rowsq_kernel<<<KCODES / 256, 256, 0, stream>>>(e, se, KCODES);
    mfma_argmin_kernel<<<N_ROWS / 128, 256, 0, stream>>>(zh, ehp, sz, se, epsr, cqmin, cnt, cand);
    rescore_kernel<<<N_ROWS / 256, 256, 0, stream>>>(z, e, sz, se, epsr, cqmin, cnt, cand, idx, out + IDX_OFF);
    zq_loss_kernel<<<ZQ_BLOCKS, 256, 0, stream>>>(z, e, idx, out, partial);
    loss_final_kernel<<<1, 256, 0, stream>>>(partial, out + LOSS_OFF);
}